// Round 1
// baseline (233.263 us; speedup 1.0000x reference)
//
#include <hip/hip_runtime.h>

// Problem constants (match reference file)
constexpr int B = 32;
constexpr int L = 512;
constexpr int D = 384;
constexpr int T = 4096;
constexpr int VPR = D / 4;            // float4 per output row = 96
constexpr int OUT0 = B * T * D;       // elements in first output
constexpr int NROWS = B * T;          // 131072
constexpr int TOTAL4 = NROWS * VPR;   // 12,582,912 float4 stores

// Kernel 1: per-batch inclusive cumsum of durations (+ write exp_dur as f32)
__global__ void scan_k(const int* __restrict__ dur, int* __restrict__ cum,
                       float* __restrict__ exp_dur_out) {
    const int b = blockIdx.x;
    const int t = threadIdx.x;
    __shared__ int s[L];
    int d = dur[b * L + t];
    // EXPAND_SCALE == 1.0 -> round(1.0 * d) == d
    exp_dur_out[b * L + t] = (float)d;
    s[t] = d;
    __syncthreads();
    #pragma unroll
    for (int off = 1; off < L; off <<= 1) {
        int v = (t >= off) ? s[t - off] : 0;
        __syncthreads();
        s[t] += v;
        __syncthreads();
    }
    cum[b * L + t] = s[t];
}

// Kernel 2: per (b, j) binary search -> source row index (or -1 for zero-fill)
__global__ void idx_k(const int* __restrict__ cum, const int* __restrict__ mask,
                      int* __restrict__ idxmap) {
    const int i = blockIdx.x * blockDim.x + threadIdx.x;
    if (i >= NROWS) return;
    const int b = i >> 12;          // / T
    const int j = i & (T - 1);      // % T
    const int* c = cum + b * L;
    const int total = c[L - 1];
    int res = -1;
    if (j < total) {
        // searchsorted(c, j, side='right'): first idx with c[idx] > j
        int lo = 0, hi = L;         // since j < total, result <= L-1
        while (lo < hi) {
            int mid = (lo + hi) >> 1;
            if (c[mid] <= j) lo = mid + 1; else hi = mid;
        }
        res = mask[b * L + lo] ? -1 : (b * L + lo);
    }
    idxmap[i] = res;
}

// Kernel 3: gather rows (or zero-fill), one float4 per thread
__global__ void gather_k(const float4* __restrict__ seq,
                         const int* __restrict__ idxmap,
                         float4* __restrict__ out) {
    const int i = blockIdx.x * blockDim.x + threadIdx.x;
    if (i >= TOTAL4) return;
    const int row = i / VPR;            // compile-time magic-mul
    const int col = i - row * VPR;
    const int src = idxmap[row];        // broadcast within wave
    float4 v = make_float4(0.f, 0.f, 0.f, 0.f);
    if (src >= 0) v = seq[src * VPR + col];
    out[i] = v;
}

extern "C" void kernel_launch(void* const* d_in, const int* in_sizes, int n_in,
                              void* d_out, int out_size, void* d_ws, size_t ws_size,
                              hipStream_t stream) {
    const float* seq  = (const float*)d_in[0];
    const int*   dur  = (const int*)d_in[1];
    const int*   mask = (const int*)d_in[2];
    // d_in[3] = max_length scalar (4096, matches T)

    float* out      = (float*)d_out;
    float* expd_out = out + OUT0;

    int* cum    = (int*)d_ws;                       // B*L*4 = 64 KB
    int* idxmap = (int*)((char*)d_ws + B * L * 4);  // NROWS*4 = 512 KB

    scan_k<<<B, L, 0, stream>>>(dur, cum, expd_out);

    {
        const int bs = 256;
        idx_k<<<(NROWS + bs - 1) / bs, bs, 0, stream>>>(cum, mask, idxmap);
    }
    {
        const int bs = 256;
        gather_k<<<(TOTAL4 + bs - 1) / bs, bs, 0, stream>>>(
            (const float4*)seq, idxmap, (float4*)out);
    }
}

// Round 2
// 217.463 us; speedup vs baseline: 1.0727x; 1.0727x over previous
//
#include <hip/hip_runtime.h>

// Problem constants (match reference file)
constexpr int B = 32;
constexpr int L = 512;
constexpr int D = 384;
constexpr int T = 4096;
constexpr int VPR = D / 4;                 // float4 per output row = 96
constexpr int OUT0 = B * T * D;            // elements in first output
constexpr int RPB = 16;                    // output rows per block
constexpr int BLOCKS_PER_BATCH = T / RPB;  // 256
constexpr int NBLK = B * BLOCKS_PER_BATCH; // 8192
constexpr int BS = 256;                    // threads per block
constexpr int PASSES = RPB * VPR / BS;     // 6

// Kernel 1: per-batch inclusive cumsum of durations (+ write exp_dur as f32)
__global__ __launch_bounds__(L) void scan_k(const int* __restrict__ dur,
                                            int* __restrict__ cum,
                                            float* __restrict__ exp_dur_out) {
    const int b = blockIdx.x;
    const int t = threadIdx.x;
    __shared__ int s[L];
    int d = dur[b * L + t];
    // EXPAND_SCALE == 1.0 -> round(1.0 * d) == d
    exp_dur_out[b * L + t] = (float)d;
    s[t] = d;
    __syncthreads();
    #pragma unroll
    for (int off = 1; off < L; off <<= 1) {
        int v = (t >= off) ? s[t - off] : 0;
        __syncthreads();
        s[t] += v;
        __syncthreads();
    }
    cum[b * L + t] = s[t];
}

// Kernel 2 (fused search + gather): each block owns RPB consecutive output
// rows of one batch. Stage cum[b][:] in LDS, binary-search the RPB row
// indices in LDS, then stream contiguous float4 stores.
__global__ __launch_bounds__(BS) void fused_k(const float4* __restrict__ seq,
                                              const int* __restrict__ cum,
                                              const int* __restrict__ mask,
                                              float4* __restrict__ out) {
    __shared__ int s_cum[L];
    __shared__ int s_src[RPB];

    const int blk   = blockIdx.x;
    const int b     = blk >> 8;            // / BLOCKS_PER_BATCH (256)
    const int chunk = blk & 255;           // % BLOCKS_PER_BATCH
    const int row0  = chunk * RPB;         // first output slot j of this block
    const int tid   = threadIdx.x;

    // stage this batch's cumulative-duration array (2 KB)
    #pragma unroll
    for (int i = 0; i < L / BS; ++i)
        s_cum[i * BS + tid] = cum[b * L + i * BS + tid];
    __syncthreads();

    // 16 binary searches in LDS (threads 0..RPB-1)
    if (tid < RPB) {
        const int j = row0 + tid;
        const int total = s_cum[L - 1];
        int res = -1;
        if (j < total) {
            int lo = 0, hi = L;            // j < total => result <= L-1
            while (lo < hi) {
                int mid = (lo + hi) >> 1;
                if (s_cum[mid] <= j) lo = mid + 1; else hi = mid;
            }
            res = mask[b * L + lo] ? -1 : (b * L + lo);
        }
        s_src[tid] = res;
    }
    __syncthreads();

    // copy loop: RPB*VPR = 1536 float4, 6 passes of 256 threads,
    // output addresses fully contiguous per block (24 KB)
    float4* obase = out + (size_t)(b * T + row0) * VPR;
    #pragma unroll
    for (int p = 0; p < PASSES; ++p) {
        const int idx = p * BS + tid;      // 0..1535
        const int r   = idx / VPR;         // constant div -> magic mul
        const int col = idx - r * VPR;
        const int s   = s_src[r];
        float4 v = make_float4(0.f, 0.f, 0.f, 0.f);
        if (s >= 0) v = seq[(size_t)s * VPR + col];
        obase[idx] = v;
    }
}

extern "C" void kernel_launch(void* const* d_in, const int* in_sizes, int n_in,
                              void* d_out, int out_size, void* d_ws, size_t ws_size,
                              hipStream_t stream) {
    const float* seq  = (const float*)d_in[0];
    const int*   dur  = (const int*)d_in[1];
    const int*   mask = (const int*)d_in[2];
    // d_in[3] = max_length scalar (4096 == T)

    float* out      = (float*)d_out;
    float* expd_out = out + OUT0;

    int* cum = (int*)d_ws;                 // B*L*4 = 64 KB scratch

    scan_k<<<B, L, 0, stream>>>(dur, cum, expd_out);
    fused_k<<<NBLK, BS, 0, stream>>>((const float4*)seq, cum, mask,
                                     (float4*)out);
}